// Round 7
// baseline (290.266 us; speedup 1.0000x reference)
//
#include <hip/hip_runtime.h>
#include <hip/hip_bf16.h>

// SelfAttention: B=4, S=2048, D=1024, fp32 in/out.
// Round 7:
//  - gemm256c structure: 256x128 tile built from the conflict-free 16x16x32
//    fragment pattern (8x4 subtiles/wave, XOR chunk swizzle) -> used by qkvt
//    and scores. (R6's 32x32 pattern had 4.7M bank-conflict cycles.)
//  - scores writes non-atomic per-(row, ntile, wavehalf) partial sums to
//    lpart[row][32]; PV preloads/reduces them to linv[] in LDS. No atomics,
//    no zero-init.
//  - XCD-aware block ordering: blocks sharing the re-read operand spaced by
//    multiples of 8 in linear block id (same XCD L2).
// 4 launches: prep, qkvt, scores, pv.

typedef _Float16 half_t;
typedef _Float16 half8 __attribute__((ext_vector_type(8)));
typedef _Float16 half4v __attribute__((ext_vector_type(4)));
typedef float f32x4 __attribute__((ext_vector_type(4)));

__device__ __forceinline__ void load16_to_lds(const half_t* g, half_t* l) {
  __builtin_amdgcn_global_load_lds(
      (const __attribute__((address_space(1))) void*)g,
      (__attribute__((address_space(3))) void*)l, 16, 0, 0);
}

// ---------------- qkvt: both weight gemms, 256x128 tile, 16x16x32 ------------
// 1D grid 768. Blocks [0,512): qk[8192,2048] = x @ [Wq|Wk]^T, m-fast (b&31)
// so same-m (shared x-rows) blocks sit 32 apart -> same XCD.
// Blocks [512,768): vtg[1024,8192] = Wv^T @ x^T, m-fast (b&3).
// LDS layout: row r, pos p holds global chunk p^(r&7); readers XOR the same.
__global__ __launch_bounds__(256) void qkvt_gemm(
    const half_t* __restrict__ xh, const half_t* __restrict__ wt,
    half_t* __restrict__ qk, half_t* __restrict__ vtg) {
  __shared__ __align__(16) half_t As[256 * 64];
  __shared__ __align__(16) half_t Bs[128 * 64];

  int b = blockIdx.x;
  const half_t* A; const half_t* Bm; half_t* C;
  int ldc, m0, n0;
  if (b < 512) {  // QK: M=8192, N=2048
    A = xh; Bm = wt; C = qk; ldc = 2048;
    m0 = (b & 31) * 256; n0 = (b >> 5) * 128;
  } else {        // VT: M=1024, N=8192
    b -= 512;
    A = wt + (size_t)2 * 1024 * 1024; Bm = xh; C = vtg; ldc = 8192;
    m0 = (b & 3) * 256; n0 = (b >> 2) * 128;
  }
  constexpr int lda = 1024, ldb = 1024, K = 1024;

  const int t    = threadIdx.x;
  const int wave = t >> 6;
  const int lane = t & 63;
  const int wm   = (wave >> 1) * 128;
  const int wn   = (wave & 1) * 64;
  const int lm   = lane & 15;
  const int lq   = lane >> 4;
  const int lswz = lm & 7;

  const int trow = t >> 3;
  const int tchk = (t & 7) ^ (trow & 7);

  const half_t* gA0 = A  + (size_t)(m0 + trow) * lda + tchk * 8;
  const half_t* gB0 = Bm + (size_t)(n0 + trow) * ldb + tchk * 8;
  const size_t stepA = (size_t)32 * lda;
  const size_t stepB = (size_t)32 * ldb;

  half_t* lA0 = &As[t * 8];
  half_t* lB0 = &Bs[t * 8];

  f32x4 acc[8][4] = {};

  for (int k0 = 0; k0 < K; k0 += 64) {
    __syncthreads();
#pragma unroll
    for (int n = 0; n < 8; ++n)
      load16_to_lds(gA0 + n * stepA + k0, lA0 + n * 2048);
#pragma unroll
    for (int n = 0; n < 4; ++n)
      load16_to_lds(gB0 + n * stepB + k0, lB0 + n * 2048);
    __syncthreads();

#pragma unroll
    for (int kk = 0; kk < 2; ++kk) {
      const int pos = ((kk * 4 + lq) ^ lswz) * 8;
      half8 a[8], bf[4];
#pragma unroll
      for (int i = 0; i < 8; ++i)
        a[i] = *(const half8*)&As[(wm + i * 16 + lm) * 64 + pos];
#pragma unroll
      for (int j = 0; j < 4; ++j)
        bf[j] = *(const half8*)&Bs[(wn + j * 16 + lm) * 64 + pos];
#pragma unroll
      for (int i = 0; i < 8; ++i)
#pragma unroll
        for (int j = 0; j < 4; ++j)
          acc[i][j] = __builtin_amdgcn_mfma_f32_16x16x32_f16(a[i], bf[j], acc[i][j], 0, 0, 0);
    }
  }

  // C/D layout: col = lane&15, row = (lane>>4)*4 + reg  [m89-verified]
#pragma unroll
  for (int i = 0; i < 8; ++i)
#pragma unroll
    for (int j = 0; j < 4; ++j) {
      const int col = n0 + wn + j * 16 + lm;
#pragma unroll
      for (int r = 0; r < 4; ++r) {
        const int row = m0 + wm + i * 16 + lq * 4 + r;
        C[(size_t)row * ldc + col] = (half_t)acc[i][j][r];
      }
    }
}

// ------------- scores: P = exp(qk^T/32 - 8), 256x128 tile + partials ---------
// Grid (8 m-tiles, 16 n-tiles, 4 b): same-m blocks 8 apart -> same XCD.
// Partial row sums: lpart[(z*2048+row)*32 + ny*2 + (wave&1)], no atomics.
__global__ __launch_bounds__(256) void scores_gemm(
    const half_t* __restrict__ qk, half_t* __restrict__ sc,
    float* __restrict__ lpart) {
  __shared__ __align__(16) half_t As[256 * 64];
  __shared__ __align__(16) half_t Bs[128 * 64];

  const int z  = blockIdx.z;
  const int m0 = blockIdx.x * 256;
  const int n0 = blockIdx.y * 128;
  const half_t* A  = qk + (size_t)z * 2048 * 2048;          // q rows
  const half_t* Bm = A + 1024;                               // k rows
  half_t* C = sc + (size_t)z * 2048 * 2048;
  constexpr int lda = 2048, ldb = 2048, ldc = 2048, K = 1024;

  const int t    = threadIdx.x;
  const int wave = t >> 6;
  const int lane = t & 63;
  const int wm   = (wave >> 1) * 128;
  const int wn   = (wave & 1) * 64;
  const int lm   = lane & 15;
  const int lq   = lane >> 4;
  const int lswz = lm & 7;

  const int trow = t >> 3;
  const int tchk = (t & 7) ^ (trow & 7);

  const half_t* gA0 = A  + (size_t)(m0 + trow) * lda + tchk * 8;
  const half_t* gB0 = Bm + (size_t)(n0 + trow) * ldb + tchk * 8;
  const size_t stepA = (size_t)32 * lda;
  const size_t stepB = (size_t)32 * ldb;

  half_t* lA0 = &As[t * 8];
  half_t* lB0 = &Bs[t * 8];

  f32x4 acc[8][4] = {};

  for (int k0 = 0; k0 < K; k0 += 64) {
    __syncthreads();
#pragma unroll
    for (int n = 0; n < 8; ++n)
      load16_to_lds(gA0 + n * stepA + k0, lA0 + n * 2048);
#pragma unroll
    for (int n = 0; n < 4; ++n)
      load16_to_lds(gB0 + n * stepB + k0, lB0 + n * 2048);
    __syncthreads();

#pragma unroll
    for (int kk = 0; kk < 2; ++kk) {
      const int pos = ((kk * 4 + lq) ^ lswz) * 8;
      half8 a[8], bf[4];
#pragma unroll
      for (int i = 0; i < 8; ++i)
        a[i] = *(const half8*)&As[(wm + i * 16 + lm) * 64 + pos];
#pragma unroll
      for (int j = 0; j < 4; ++j)
        bf[j] = *(const half8*)&Bs[(wn + j * 16 + lm) * 64 + pos];
#pragma unroll
      for (int i = 0; i < 8; ++i)
#pragma unroll
        for (int j = 0; j < 4; ++j)
          acc[i][j] = __builtin_amdgcn_mfma_f32_16x16x32_f16(a[i], bf[j], acc[i][j], 0, 0, 0);
    }
  }

  const float scale = 1.0f / 32.0f;
#pragma unroll
  for (int i = 0; i < 8; ++i)
#pragma unroll
    for (int r = 0; r < 4; ++r) {
      const int row = m0 + wm + i * 16 + lq * 4 + r;
      float s = 0.f;
#pragma unroll
      for (int j = 0; j < 4; ++j) {
        const int col = n0 + wn + j * 16 + lm;
        float v = __expf(acc[i][j][r] * scale - 8.0f);
        s += v;
        C[(size_t)row * ldc + col] = (half_t)v;
      }
      s += __shfl_xor(s, 1); s += __shfl_xor(s, 2);
      s += __shfl_xor(s, 4); s += __shfl_xor(s, 8);
      if (lm == 0)
        lpart[((size_t)z * 2048 + row) * 32 + blockIdx.y * 2 + (wave & 1)] = s;
    }
}

// --------------- pv: out = (P @ V) / l, 128x128 tile, 16x16x32 ---------------
// Grid (16 q-tiles, 8 d-tiles, 4 b): same-q blocks 16 apart -> same XCD
// (P row-block stays L2-resident across its 8 d-blocks).
__global__ __launch_bounds__(256) void pv_gemm(
    const half_t* __restrict__ sc, const half_t* __restrict__ vtg,
    float* __restrict__ out, const float* __restrict__ lpart) {
  __shared__ __align__(16) half_t As[128 * 64];
  __shared__ __align__(16) half_t Bs[128 * 64];
  __shared__ float linv[128];

  const int z  = blockIdx.z;
  const int m0 = blockIdx.x * 128;
  const int n0 = blockIdx.y * 128;
  const half_t* A  = sc  + (size_t)z * 2048 * 2048;
  const half_t* Bm = vtg + (size_t)z * 2048;
  float* C = out + (size_t)z * 2048 * 1024;
  constexpr int lda = 2048, ldb = 8192, ldc = 1024, K = 2048;

  const int t    = threadIdx.x;
  const int wave = t >> 6;
  const int lane = t & 63;
  const int wm   = (wave >> 1) * 64;
  const int wn   = (wave & 1) * 64;
  const int lm   = lane & 15;
  const int lq   = lane >> 4;
  const int lswz = lm & 7;

  // Reduce the 32 per-row partials to 1/l (covered by the loop's first barrier)
  if (t < 128) {
    const float4* lp =
        (const float4*)&lpart[((size_t)z * 2048 + m0 + t) * 32];
    float s = 0.f;
#pragma unroll
    for (int p = 0; p < 8; ++p) {
      float4 v = lp[p];
      s += v.x + v.y + v.z + v.w;
    }
    linv[t] = 1.0f / s;
  }

  const int trow = t >> 3;
  const int tchk = (t & 7) ^ (trow & 7);

  const half_t* gA0 = A  + (size_t)(m0 + trow) * lda + tchk * 8;
  const half_t* gB0 = Bm + (size_t)(n0 + trow) * ldb + tchk * 8;
  const size_t stepA = (size_t)32 * lda;
  const size_t stepB = (size_t)32 * ldb;

  half_t* lA0 = &As[t * 8];
  half_t* lB0 = &Bs[t * 8];

  f32x4 acc[4][4] = {};

  for (int k0 = 0; k0 < K; k0 += 64) {
    __syncthreads();
#pragma unroll
    for (int n = 0; n < 4; ++n) {
      load16_to_lds(gA0 + n * stepA + k0, lA0 + n * 2048);
      load16_to_lds(gB0 + n * stepB + k0, lB0 + n * 2048);
    }
    __syncthreads();

#pragma unroll
    for (int kk = 0; kk < 2; ++kk) {
      const int pos = ((kk * 4 + lq) ^ lswz) * 8;
      half8 a[4], bf[4];
#pragma unroll
      for (int i = 0; i < 4; ++i)
        a[i] = *(const half8*)&As[(wm + i * 16 + lm) * 64 + pos];
#pragma unroll
      for (int j = 0; j < 4; ++j)
        bf[j] = *(const half8*)&Bs[(wn + j * 16 + lm) * 64 + pos];
#pragma unroll
      for (int i = 0; i < 4; ++i)
#pragma unroll
        for (int j = 0; j < 4; ++j)
          acc[i][j] = __builtin_amdgcn_mfma_f32_16x16x32_f16(a[i], bf[j], acc[i][j], 0, 0, 0);
    }
  }

#pragma unroll
  for (int i = 0; i < 4; ++i)
#pragma unroll
    for (int r = 0; r < 4; ++r) {
      const int lrow = wm + i * 16 + lq * 4 + r;
      const float inv = linv[lrow];
      const int row = m0 + lrow;
#pragma unroll
      for (int j = 0; j < 4; ++j) {
        const int col = n0 + wn + j * 16 + lm;
        C[(size_t)row * ldc + col] = acc[i][j][r] * inv;
      }
    }
}

// --------------- prep: cast x + transpose weights (1 launch) -----------------
__global__ __launch_bounds__(256) void prep(
    const float* __restrict__ x, half_t* __restrict__ xh,
    const float* __restrict__ Wq, const float* __restrict__ Wk,
    const float* __restrict__ Wv, half_t* __restrict__ wt) {
  __shared__ half_t tile[32][33];
  const int b = blockIdx.x;
  const int t = threadIdx.x;
  if (b < 8192) {
    const int i = (b * 256 + t) * 4;
    const float4 v = *reinterpret_cast<const float4*>(x + i);
    half4v o;
    o.x = (half_t)v.x; o.y = (half_t)v.y; o.z = (half_t)v.z; o.w = (half_t)v.w;
    *reinterpret_cast<half4v*>(xh + i) = o;
  } else {
    int bb = b - 8192;
    const int w = bb >> 10; bb &= 1023;
    const float* in = (w == 0) ? Wq : (w == 1) ? Wk : Wv;
    half_t* o = wt + (size_t)w * 1024 * 1024;
    const int r0 = (bb >> 5) * 32, c0 = (bb & 31) * 32;
    const int tx = t & 31, ty = t >> 5;
#pragma unroll
    for (int i = 0; i < 32; i += 8)
      tile[ty + i][tx] = (half_t)in[(size_t)(r0 + ty + i) * 1024 + c0 + tx];
    __syncthreads();
#pragma unroll
    for (int i = 0; i < 32; i += 8)
      o[(size_t)(c0 + ty + i) * 1024 + r0 + tx] = tile[tx][ty + i];
  }
}

extern "C" void kernel_launch(void* const* d_in, const int* in_sizes, int n_in,
                              void* d_out, int out_size, void* d_ws, size_t ws_size,
                              hipStream_t stream) {
  constexpr int Bb = 4, S = 2048, D = 1024;
  constexpr size_t MS = (size_t)Bb * S;  // 8192 rows

  const float* x  = (const float*)d_in[0];
  const float* Wq = (const float*)d_in[1];
  const float* Wk = (const float*)d_in[2];
  const float* Wv = (const float*)d_in[3];
  float* out = (float*)d_out;

  // Workspace carve (~103 MB).
  char* p = (char*)d_ws;
  half_t* xh    = (half_t*)p; p += MS * D * 2;               // 16 MB
  half_t* wt    = (half_t*)p; p += (size_t)3 * D * D * 2;    // 6 MB  [Wq|Wk|Wv]^T
  half_t* qk    = (half_t*)p; p += MS * (size_t)(2 * D) * 2; // 32 MB [B*S, 2D]
  half_t* vtg   = (half_t*)p; p += (size_t)D * MS * 2;       // 16 MB [D, B*S]
  half_t* sc    = (half_t*)p; p += (size_t)Bb * S * S * 2;   // 32 MB P=exp(s-8)
  float*  lpart = (float*)p;  p += MS * 32 * 4;              // 1 MB partial sums

  prep<<<11264, 256, 0, stream>>>(x, xh, Wq, Wk, Wv, wt);
  qkvt_gemm<<<768, 256, 0, stream>>>(xh, wt, qk, vtg);
  scores_gemm<<<dim3(8, 16, Bb), 256, 0, stream>>>(qk, sc, lpart);
  pv_gemm<<<dim3(16, 8, Bb), 256, 0, stream>>>(sc, vtg, out, lpart);
}

// Round 8
// 241.702 us; speedup vs baseline: 1.2009x; 1.2009x over previous
//
#include <hip/hip_runtime.h>
#include <hip/hip_bf16.h>

// SelfAttention: B=4, S=2048, D=1024, fp32 in/out.
// Round 8: best-of-measured assembly.
//  - qkvt: R6's 32x32x16 256x128-tile kernel verbatim (74us measured; its
//    4-way LDS read aliasing costs ~7us -- cheaper than the 156-VGPR
//    "conflict-free" variant which cost 38us. R7 post-mortem.)
//  - scores: R5's 128x128 16x16x32 gemm (53.4us measured), epilogue writes
//    NON-atomic per-(row, n-tile, wave-half) partials lpart[row][32].
//  - pv: gemm128 + lpart->linv LDS preamble + XCD-friendly grid.
//  - prep: cast x + 3 weight transposes (no lb zero needed).
// 4 launches: prep, qkvt, scores, pv.

typedef _Float16 half_t;
typedef _Float16 half8 __attribute__((ext_vector_type(8)));
typedef _Float16 half4v __attribute__((ext_vector_type(4)));
typedef float f32x4 __attribute__((ext_vector_type(4)));
typedef float f32x16 __attribute__((ext_vector_type(16)));

__device__ __forceinline__ void load16_to_lds(const half_t* g, half_t* l) {
  __builtin_amdgcn_global_load_lds(
      (const __attribute__((address_space(1))) void*)g,
      (__attribute__((address_space(3))) void*)l, 16, 0, 0);
}

// ------------- qkvt: combined weight gemms, 256x128 tile, 32x32x16 -----------
// 1D grid of 768 blocks (= 3/CU). Blocks [0,512): qk[8192,2048] = x@[Wq|Wk]^T.
// Blocks [512,768): vtg[1024,8192] = Wv^T @ x^T (v transposed, directly).
// K=1024 compile-time. LDS: row r, pos p holds global chunk p^(r&7).
__global__ __launch_bounds__(256, 2) void qkvt_gemm(
    const half_t* __restrict__ xh, const half_t* __restrict__ wt,
    half_t* __restrict__ qk, half_t* __restrict__ vtg) {
  __shared__ __align__(16) half_t As[256 * 64];
  __shared__ __align__(16) half_t Bs[128 * 64];

  constexpr int K = 1024;
  int b = blockIdx.x;
  const half_t* A; const half_t* Bm; half_t* C;
  int lda, ldb, ldc, m0, n0;
  if (b < 512) {  // QK: M=8192, N=2048
    A = xh; Bm = wt; C = qk; lda = 1024; ldb = 1024; ldc = 2048;
    m0 = (b >> 4) * 256; n0 = (b & 15) * 128;
  } else {        // VT: M=1024, N=8192
    b -= 512;
    A = wt + (size_t)2 * 1024 * 1024; Bm = xh; C = vtg;
    lda = 1024; ldb = 1024; ldc = 8192;
    m0 = (b >> 6) * 256; n0 = (b & 63) * 128;
  }

  const int t    = threadIdx.x;
  const int wave = t >> 6;
  const int lane = t & 63;
  const int wm   = (wave >> 1) * 128;
  const int wn   = (wave & 1) * 64;
  const int ln   = lane & 31;
  const int hl   = lane >> 5;
  const int lswz = ln & 7;

  const int trow = t >> 3;
  const int tchk = (t & 7) ^ (trow & 7);

  const half_t* gA0 = A  + (size_t)(m0 + trow) * lda + tchk * 8;
  const half_t* gB0 = Bm + (size_t)(n0 + trow) * ldb + tchk * 8;
  const size_t stepA = (size_t)32 * lda;
  const size_t stepB = (size_t)32 * ldb;

  half_t* lA0 = &As[t * 8];
  half_t* lB0 = &Bs[t * 8];

  f32x16 acc[4][2] = {};

  for (int k0 = 0; k0 < K; k0 += 64) {
    __syncthreads();
#pragma unroll
    for (int n = 0; n < 8; ++n)
      load16_to_lds(gA0 + n * stepA + k0, lA0 + n * 2048);
#pragma unroll
    for (int n = 0; n < 4; ++n)
      load16_to_lds(gB0 + n * stepB + k0, lB0 + n * 2048);
    __syncthreads();

#pragma unroll
    for (int kk = 0; kk < 4; ++kk) {
      const int c = kk * 2 + hl;
      half8 a[4], bfr[2];
#pragma unroll
      for (int i = 0; i < 4; ++i)
        a[i] = *(const half8*)&As[(wm + i * 32 + ln) * 64 + (c ^ lswz) * 8];
#pragma unroll
      for (int j = 0; j < 2; ++j)
        bfr[j] = *(const half8*)&Bs[(wn + j * 32 + ln) * 64 + (c ^ lswz) * 8];
#pragma unroll
      for (int i = 0; i < 4; ++i)
#pragma unroll
        for (int j = 0; j < 2; ++j)
          acc[i][j] = __builtin_amdgcn_mfma_f32_32x32x16_f16(a[i], bfr[j], acc[i][j], 0, 0, 0);
    }
  }

  // 32x32 C/D: col=lane&31, row=(reg&3)+8*(reg>>2)+4*(lane>>5)  [m74/m101]
#pragma unroll
  for (int i = 0; i < 4; ++i)
#pragma unroll
    for (int j = 0; j < 2; ++j) {
      const int col = n0 + wn + j * 32 + ln;
#pragma unroll
      for (int reg = 0; reg < 16; ++reg) {
        const int row = m0 + wm + i * 32 + 4 * hl + (reg & 3) + 8 * (reg >> 2);
        C[(size_t)row * ldc + col] = (half_t)acc[i][j][reg];
      }
    }
}

// ------------- scores: P = exp(qk^T/32 - 8), 128x128 tile, 16x16x32 ----------
// Grid (16 n-tiles, 16 m-tiles, 4 b) — R5's measured-53us shape. Epilogue
// writes non-atomic partials lpart[(z*2048+row)*32 + nx*2 + (wave&1)].
// LDS XOR swizzle: conflict-free (R3/R5 measured 0).
__global__ __launch_bounds__(256) void scores_gemm(
    const half_t* __restrict__ qk, half_t* __restrict__ sc,
    float* __restrict__ lpart) {
  __shared__ __align__(16) half_t As[128 * 64];
  __shared__ __align__(16) half_t Bs[128 * 64];

  const int z  = blockIdx.z;
  const int m0 = blockIdx.y * 128;
  const int n0 = blockIdx.x * 128;
  const half_t* A  = qk + (size_t)z * 2048 * 2048;  // q rows (ld 2048)
  const half_t* Bm = A + 1024;                      // k rows
  half_t* C = sc + (size_t)z * 2048 * 2048;
  constexpr int lda = 2048, ldb = 2048, ldc = 2048, K = 1024;

  const int t    = threadIdx.x;
  const int wave = t >> 6;
  const int lane = t & 63;
  const int wm   = (wave >> 1) * 64;
  const int wn   = (wave & 1) * 64;
  const int lm   = lane & 15;
  const int lq   = lane >> 4;
  const int lswz = lm & 7;

  const int trow = t >> 3;
  const int tchk = (t & 7) ^ (trow & 7);

  const half_t* gA0 = A  + (size_t)(m0 + trow) * lda + tchk * 8;
  const half_t* gB0 = Bm + (size_t)(n0 + trow) * ldb + tchk * 8;
  const size_t stepA = (size_t)32 * lda;
  const size_t stepB = (size_t)32 * ldb;

  half_t* lA0 = &As[t * 8];
  half_t* lB0 = &Bs[t * 8];

  f32x4 acc[4][4] = {};

  for (int k0 = 0; k0 < K; k0 += 64) {
    __syncthreads();
#pragma unroll
    for (int n = 0; n < 4; ++n) {
      load16_to_lds(gA0 + n * stepA + k0, lA0 + n * 2048);
      load16_to_lds(gB0 + n * stepB + k0, lB0 + n * 2048);
    }
    __syncthreads();

#pragma unroll
    for (int kk = 0; kk < 2; ++kk) {
      const int pos = ((kk * 4 + lq) ^ lswz) * 8;
      half8 a[4], bf[4];
#pragma unroll
      for (int i = 0; i < 4; ++i)
        a[i] = *(const half8*)&As[(wm + i * 16 + lm) * 64 + pos];
#pragma unroll
      for (int j = 0; j < 4; ++j)
        bf[j] = *(const half8*)&Bs[(wn + j * 16 + lm) * 64 + pos];
#pragma unroll
      for (int i = 0; i < 4; ++i)
#pragma unroll
        for (int j = 0; j < 4; ++j)
          acc[i][j] = __builtin_amdgcn_mfma_f32_16x16x32_f16(a[i], bf[j], acc[i][j], 0, 0, 0);
    }
  }

  const float scale = 1.0f / 32.0f;
#pragma unroll
  for (int i = 0; i < 4; ++i)
#pragma unroll
    for (int r = 0; r < 4; ++r) {
      const int row = m0 + wm + i * 16 + lq * 4 + r;
      float s = 0.f;
#pragma unroll
      for (int j = 0; j < 4; ++j) {
        const int col = n0 + wn + j * 16 + lm;
        float v = __expf(acc[i][j][r] * scale - 8.0f);
        s += v;
        C[(size_t)row * ldc + col] = (half_t)v;
      }
      // reduce across the 16-lane quad group; one store per (row, block, half)
      s += __shfl_xor(s, 1); s += __shfl_xor(s, 2);
      s += __shfl_xor(s, 4); s += __shfl_xor(s, 8);
      if (lm == 0)
        lpart[((size_t)z * 2048 + row) * 32 + blockIdx.x * 2 + (wave & 1)] = s;
    }
}

// --------------- pv: out = (P @ V) / l, 128x128 tile, 16x16x32 ---------------
// Grid (16 q-tiles, 8 d-tiles, 4 b): same-q blocks 16 apart -> same XCD
// (P row-block stays L2-resident across its 8 d-blocks).
__global__ __launch_bounds__(256) void pv_gemm(
    const half_t* __restrict__ sc, const half_t* __restrict__ vtg,
    float* __restrict__ out, const float* __restrict__ lpart) {
  __shared__ __align__(16) half_t As[128 * 64];
  __shared__ __align__(16) half_t Bs[128 * 64];
  __shared__ float linv[128];

  const int z  = blockIdx.z;
  const int m0 = blockIdx.x * 128;
  const int n0 = blockIdx.y * 128;
  const half_t* A  = sc  + (size_t)z * 2048 * 2048;
  const half_t* Bm = vtg + (size_t)z * 2048;
  float* C = out + (size_t)z * 2048 * 1024;
  constexpr int lda = 2048, ldb = 8192, ldc = 1024, K = 2048;

  const int t    = threadIdx.x;
  const int wave = t >> 6;
  const int lane = t & 63;
  const int wm   = (wave >> 1) * 64;
  const int wn   = (wave & 1) * 64;
  const int lm   = lane & 15;
  const int lq   = lane >> 4;
  const int lswz = lm & 7;

  // Reduce 32 per-row partials to 1/l (covered by the loop's first barrier)
  if (t < 128) {
    const float4* lp = (const float4*)&lpart[((size_t)z * 2048 + m0 + t) * 32];
    float s = 0.f;
#pragma unroll
    for (int p = 0; p < 8; ++p) {
      float4 v = lp[p];
      s += v.x + v.y + v.z + v.w;
    }
    linv[t] = 1.0f / s;
  }

  const int trow = t >> 3;
  const int tchk = (t & 7) ^ (trow & 7);

  const half_t* gA0 = A  + (size_t)(m0 + trow) * lda + tchk * 8;
  const half_t* gB0 = Bm + (size_t)(n0 + trow) * ldb + tchk * 8;
  const size_t stepA = (size_t)32 * lda;
  const size_t stepB = (size_t)32 * ldb;

  half_t* lA0 = &As[t * 8];
  half_t* lB0 = &Bs[t * 8];

  f32x4 acc[4][4] = {};

  for (int k0 = 0; k0 < K; k0 += 64) {
    __syncthreads();
#pragma unroll
    for (int n = 0; n < 4; ++n) {
      load16_to_lds(gA0 + n * stepA + k0, lA0 + n * 2048);
      load16_to_lds(gB0 + n * stepB + k0, lB0 + n * 2048);
    }
    __syncthreads();

#pragma unroll
    for (int kk = 0; kk < 2; ++kk) {
      const int pos = ((kk * 4 + lq) ^ lswz) * 8;
      half8 a[4], bf[4];
#pragma unroll
      for (int i = 0; i < 4; ++i)
        a[i] = *(const half8*)&As[(wm + i * 16 + lm) * 64 + pos];
#pragma unroll
      for (int j = 0; j < 4; ++j)
        bf[j] = *(const half8*)&Bs[(wn + j * 16 + lm) * 64 + pos];
#pragma unroll
      for (int i = 0; i < 4; ++i)
#pragma unroll
        for (int j = 0; j < 4; ++j)
          acc[i][j] = __builtin_amdgcn_mfma_f32_16x16x32_f16(a[i], bf[j], acc[i][j], 0, 0, 0);
    }
  }

#pragma unroll
  for (int i = 0; i < 4; ++i)
#pragma unroll
    for (int r = 0; r < 4; ++r) {
      const int lrow = wm + i * 16 + lq * 4 + r;
      const float inv = linv[lrow];
      const int row = m0 + lrow;
#pragma unroll
      for (int j = 0; j < 4; ++j) {
        const int col = n0 + wn + j * 16 + lm;
        C[(size_t)row * ldc + col] = acc[i][j][r] * inv;
      }
    }
}

// --------------- prep: cast x + transpose weights (1 launch) -----------------
__global__ __launch_bounds__(256) void prep(
    const float* __restrict__ x, half_t* __restrict__ xh,
    const float* __restrict__ Wq, const float* __restrict__ Wk,
    const float* __restrict__ Wv, half_t* __restrict__ wt) {
  __shared__ half_t tile[32][33];
  const int b = blockIdx.x;
  const int t = threadIdx.x;
  if (b < 8192) {
    const int i = (b * 256 + t) * 4;
    const float4 v = *reinterpret_cast<const float4*>(x + i);
    half4v o;
    o.x = (half_t)v.x; o.y = (half_t)v.y; o.z = (half_t)v.z; o.w = (half_t)v.w;
    *reinterpret_cast<half4v*>(xh + i) = o;
  } else {
    int bb = b - 8192;
    const int w = bb >> 10; bb &= 1023;
    const float* in = (w == 0) ? Wq : (w == 1) ? Wk : Wv;
    half_t* o = wt + (size_t)w * 1024 * 1024;
    const int r0 = (bb >> 5) * 32, c0 = (bb & 31) * 32;
    const int tx = t & 31, ty = t >> 5;
#pragma unroll
    for (int i = 0; i < 32; i += 8)
      tile[ty + i][tx] = (half_t)in[(size_t)(r0 + ty + i) * 1024 + c0 + tx];
    __syncthreads();
#pragma unroll
    for (int i = 0; i < 32; i += 8)
      o[(size_t)(c0 + ty + i) * 1024 + r0 + tx] = tile[tx][ty + i];
  }
}

extern "C" void kernel_launch(void* const* d_in, const int* in_sizes, int n_in,
                              void* d_out, int out_size, void* d_ws, size_t ws_size,
                              hipStream_t stream) {
  constexpr int Bb = 4, S = 2048, D = 1024;
  constexpr size_t MS = (size_t)Bb * S;  // 8192 rows

  const float* x  = (const float*)d_in[0];
  const float* Wq = (const float*)d_in[1];
  const float* Wk = (const float*)d_in[2];
  const float* Wv = (const float*)d_in[3];
  float* out = (float*)d_out;

  // Workspace carve (~103 MB).
  char* p = (char*)d_ws;
  half_t* xh    = (half_t*)p; p += MS * D * 2;               // 16 MB
  half_t* wt    = (half_t*)p; p += (size_t)3 * D * D * 2;    // 6 MB  [Wq|Wk|Wv]^T
  half_t* qk    = (half_t*)p; p += MS * (size_t)(2 * D) * 2; // 32 MB [B*S, 2D]
  half_t* vtg   = (half_t*)p; p += (size_t)D * MS * 2;       // 16 MB [D, B*S]
  half_t* sc    = (half_t*)p; p += (size_t)Bb * S * S * 2;   // 32 MB P=exp(s-8)
  float*  lpart = (float*)p;  p += MS * 32 * 4;              // 1 MB partial sums

  prep<<<11264, 256, 0, stream>>>(x, xh, Wq, Wk, Wv, wt);
  qkvt_gemm<<<768, 256, 0, stream>>>(xh, wt, qk, vtg);
  scores_gemm<<<dim3(16, 16, Bb), 256, 0, stream>>>(qk, sc, lpart);
  pv_gemm<<<dim3(16, 8, Bb), 256, 0, stream>>>(sc, vtg, out, lpart);
}